// Round 3
// baseline (32849.670 us; speedup 1.0000x reference)
//
#include <hip/hip_runtime.h>

typedef __attribute__((ext_vector_type(8))) __bf16 bf16x8;
typedef __attribute__((ext_vector_type(4))) float f32x4;
typedef __attribute__((ext_vector_type(2))) float f32x2;
typedef __attribute__((ext_vector_type(4))) unsigned int u32x4;
typedef unsigned int u32;
typedef unsigned long long u64;

#define NSEQ 32
#define TTOT 2048
#define DIM  512
#define HID  512
#define G4   2048   // 4*H
#define TAGM 0x0000ffff0000ffffull

__device__ __forceinline__ float sigmoidf_(float x) {
    return 1.0f / (1.0f + __expf(-x));
}
__device__ __forceinline__ float tanhf_(float x) {
    return 2.0f / (1.0f + __expf(-2.0f * x)) - 1.0f;
}

// comm buffer hctag: [8 slots][2 seq-groups][16 chunks][512 u32]  (slot stride 16384 u32)
// chunk (i,j) = h(seqs i*16..i*16+15, cols j*32..j*32+31), u32 = bf16<<16 | tag(t+1)

// ---------------- init ----------------
__global__ void lstm_init(const float* __restrict__ Wx, const float* __restrict__ Wh,
                          const float* __restrict__ h0,
                          __bf16* __restrict__ WxbT, __bf16* __restrict__ WhbT,
                          u32* __restrict__ hctag, float* __restrict__ cstate,
                          int* __restrict__ progress)
{
    int idx = blockIdx.x * 256 + threadIdx.x;   // 0 .. 2048*512-1
    int c = idx & (G4 - 1);
    int k = idx >> 11;
    WxbT[(size_t)c * DIM + k] = (__bf16)Wx[idx];
    WhbT[(size_t)c * HID + k] = (__bf16)Wh[idx];
    if (idx < 8 * 16384) {                      // scrub all 8 ring slots
        u32 v = 0;
        int slot = idx >> 14;
        if (slot == 0) {                        // seed slot 0 = h_0, tag 1
            int rem = idx & 16383;
            int i = rem >> 13, j = (rem >> 9) & 15, s = (rem >> 5) & 15, cc = rem & 31;
            int n = i * 16 + s, col = j * 32 + cc;
            __bf16 hb = (__bf16)h0[n * HID + col];
            v = ((u32)__builtin_bit_cast(unsigned short, hb) << 16) | 1u;
        }
        hctag[idx] = v;
    }
    if (idx < NSEQ * HID) cstate[idx] = 0.0f;
    if (idx < 32) progress[idx] = -1;
}

// ---------------- stage 1: A = x @ Wx + b (unchanged) ----------------
__global__ __launch_bounds__(256) void gemm_xwx(
    const float* __restrict__ x, const __bf16* __restrict__ WxbT,
    const float* __restrict__ b, float* __restrict__ Axw, int t0, int ltc)
{
    const int Tc   = 1 << ltc;
    const int cb   = blockIdx.x * 128;
    const int m0   = blockIdx.y * 128;
    const int tid  = threadIdx.x;
    const int w    = tid >> 6;
    const int lane = tid & 63;
    const int l15  = lane & 15;
    const int lq   = lane >> 4;
    const int wm   = w >> 1, wn = w & 1;

    f32x4 acc[4][4] = {};

    const float* xrow[4];
#pragma unroll
    for (int mi = 0; mi < 4; ++mi) {
        int r  = m0 + wm * 64 + mi * 16 + l15;
        int n  = r >> ltc;
        int tl = r & (Tc - 1);
        xrow[mi] = x + ((size_t)n * TTOT + (t0 + tl)) * DIM;
    }
    const __bf16* bcol[4];
#pragma unroll
    for (int ni = 0; ni < 4; ++ni)
        bcol[ni] = WxbT + (size_t)(cb + wn * 64 + ni * 16 + l15) * DIM;

    for (int k0 = 0; k0 < DIM; k0 += 32) {
        bf16x8 af[4], bfr[4];
#pragma unroll
        for (int mi = 0; mi < 4; ++mi) {
            const float* p = xrow[mi] + k0 + lq * 8;
            f32x4 f0 = *(const f32x4*)p;
            f32x4 f1 = *(const f32x4*)(p + 4);
            bf16x8 a;
            a[0] = (__bf16)f0[0]; a[1] = (__bf16)f0[1]; a[2] = (__bf16)f0[2]; a[3] = (__bf16)f0[3];
            a[4] = (__bf16)f1[0]; a[5] = (__bf16)f1[1]; a[6] = (__bf16)f1[2]; a[7] = (__bf16)f1[3];
            af[mi] = a;
        }
#pragma unroll
        for (int ni = 0; ni < 4; ++ni)
            bfr[ni] = *(const bf16x8*)(bcol[ni] + k0 + lq * 8);
#pragma unroll
        for (int mi = 0; mi < 4; ++mi)
#pragma unroll
            for (int ni = 0; ni < 4; ++ni)
                acc[mi][ni] = __builtin_amdgcn_mfma_f32_16x16x32_bf16(af[mi], bfr[ni], acc[mi][ni], 0, 0, 0);
    }

#pragma unroll
    for (int ni = 0; ni < 4; ++ni) {
        int col = cb + wn * 64 + ni * 16 + l15;
        float bias = b[col];
#pragma unroll
        for (int mi = 0; mi < 4; ++mi) {
#pragma unroll
            for (int j = 0; j < 4; ++j) {
                int r  = m0 + wm * 64 + mi * 16 + lq * 4 + j;
                int n  = r >> ltc;
                int tl = r & (Tc - 1);
                Axw[((size_t)n * Tc + tl) * G4 + col] = acc[mi][ni][j] + bias;
            }
        }
    }
}

// ---------------- stage 2: 2x16 partitioned recurrence, chunked polling ----------------
// WG g: seq-group i=g>>4 (16 seqs), col-chunk j=g&15 (h-cols j*32..+32, gate cols
// {q*512 + j*32 + c}). Wave w owns gate quadrant w (32 cols = 2 N-tiles).
// K-tile kt == chunk kt: poll 2KB tagged chunk straight into A-frags (no LDS staging).
__global__ __launch_bounds__(256, 1) void lstm_rec(
    const float* __restrict__ Axw,    // [32][Tc][2048]
    const __bf16* __restrict__ WhbT,  // [2048][512]
    u32* __restrict__ hctag,          // ring
    float* __restrict__ cstate,       // [32][512]
    int* __restrict__ progress,       // [32] : [i][j]
    float* __restrict__ out,          // [32][2048][512]
    int t0, int Tc)
{
    const int g    = blockIdx.x;
    const int i    = g >> 4;
    const int j    = g & 15;
    const int tid  = threadIdx.x;
    const int w    = tid >> 6;        // gate quadrant
    const int lane = tid & 63;
    const int l15  = lane & 15;
    const int lq   = lane >> 4;
    const int aoff = l15 * 16 + lq * 4;   // u64 offset within a chunk (row l15, k-cols lq*8..+8)

    // persistent Wh B-fragments: 2 N-tiles x 16 K-tiles
    bf16x8 bfrag[2][16];
#pragma unroll
    for (int n = 0; n < 2; ++n) {
        const __bf16* base = WhbT + (size_t)(w * 512 + j * 32 + n * 16 + l15) * HID + lq * 8;
#pragma unroll
        for (int kt = 0; kt < 16; ++kt)
            bfrag[n][kt] = *(const bf16x8*)(base + kt * 32);
    }

    // gate-phase mapping: thread -> (seq s, col-pair cp)
    const int s   = tid >> 4;         // 0..15
    const int cp  = tid & 15;
    const int seq = i * 16 + s;
    const int hc0 = j * 32 + 2 * cp;
    float c0 = cstate[seq * HID + hc0];
    float c1 = cstate[seq * HID + hc0 + 1];

    __shared__ float S_lds[4][16][35];

    for (int t = t0; t < t0 + Tc; ++t) {
        // flow-control probe (result consumed much later; latency hidden)
        int pl = 0x7fffffff;
        if (lane < 16)
            pl = __hip_atomic_load(&progress[i * 16 + lane], __ATOMIC_RELAXED,
                                   __HIP_MEMORY_SCOPE_AGENT);

        // Axw prefetch: 4 gate values x 2 cols (plain loads; gemm dispatch already retired)
        const float* Ap = Axw + ((size_t)seq * Tc + (t - t0)) * G4 + hc0;
        f32x2 ax0 = *(const f32x2*)(Ap);
        f32x2 ax1 = *(const f32x2*)(Ap + 512);
        f32x2 ax2 = *(const f32x2*)(Ap + 1024);
        f32x2 ax3 = *(const f32x2*)(Ap + 1536);

        const u64* hbase = (const u64*)(hctag + (size_t)(t & 7) * 16384) + (size_t)i * 4096;
        const u32 etag = (u32)(t + 1);
        const u64 pat  = (u64)etag | ((u64)etag << 32);

        // issue ALL 16 chunk loads up-front (deep prefetch; ~1 IF latency total)
        u64 va[16][4];
#pragma unroll
        for (int n = 0; n < 16; ++n) {
            const int kc = (j + n) & 15;
            const u64* p = hbase + kc * 256 + aoff;
#pragma unroll
            for (int e = 0; e < 4; ++e)
                va[n][e] = __hip_atomic_load((u64*)(p + e), __ATOMIC_RELAXED,
                                             __HIP_MEMORY_SCOPE_AGENT);
        }

        f32x4 acc0 = {0, 0, 0, 0}, acc1 = {0, 0, 0, 0};
#pragma unroll
        for (int n = 0; n < 16; ++n) {
            const int kc = (j + n) & 15;
            const u64* p = hbase + kc * 256 + aoff;
            bool ok = (((va[n][0] ^ pat) & TAGM) == 0ull) &&
                      (((va[n][1] ^ pat) & TAGM) == 0ull) &&
                      (((va[n][2] ^ pat) & TAGM) == 0ull) &&
                      (((va[n][3] ^ pat) & TAGM) == 0ull);
            while (!__all(ok)) {
#pragma unroll
                for (int e = 0; e < 4; ++e)
                    va[n][e] = __hip_atomic_load((u64*)(p + e), __ATOMIC_RELAXED,
                                                 __HIP_MEMORY_SCOPE_AGENT);
                ok = (((va[n][0] ^ pat) & TAGM) == 0ull) &&
                     (((va[n][1] ^ pat) & TAGM) == 0ull) &&
                     (((va[n][2] ^ pat) & TAGM) == 0ull) &&
                     (((va[n][3] ^ pat) & TAGM) == 0ull);
            }
            // strip tags: u64 [w1:w0] -> packed bf16 pair (hi16 of each)
            u32 q0 = ((u32)(va[n][0] >> 16) & 0xffffu) | ((u32)(va[n][0] >> 32) & 0xffff0000u);
            u32 q1 = ((u32)(va[n][1] >> 16) & 0xffffu) | ((u32)(va[n][1] >> 32) & 0xffff0000u);
            u32 q2 = ((u32)(va[n][2] >> 16) & 0xffffu) | ((u32)(va[n][2] >> 32) & 0xffff0000u);
            u32 q3 = ((u32)(va[n][3] >> 16) & 0xffffu) | ((u32)(va[n][3] >> 32) & 0xffff0000u);
            bf16x8 a = __builtin_bit_cast(bf16x8, (u32x4){q0, q1, q2, q3});
            acc0 = __builtin_amdgcn_mfma_f32_16x16x32_bf16(a, bfrag[0][kc], acc0, 0, 0, 0);
            acc1 = __builtin_amdgcn_mfma_f32_16x16x32_bf16(a, bfrag[1][kc], acc1, 0, 0, 0);
        }

        // cross-wave gate exchange (C/D layout: col=lane&15, row=lq*4+jj)
        __syncthreads();   // prior-step S_lds readers done
#pragma unroll
        for (int jj = 0; jj < 4; ++jj) {
            S_lds[w][lq * 4 + jj][l15]      = acc0[jj];
            S_lds[w][lq * 4 + jj][16 + l15] = acc1[jj];
        }
        __syncthreads();

        // all waves past K-loop => h_t fully consumed by this WG
        if (tid == 0)
            __hip_atomic_exchange(&progress[g], t, __ATOMIC_RELAXED, __HIP_MEMORY_SCOPE_AGENT);

        // enforce ring flow control before overwriting slot (t+1)&7 (holds h_{t-7})
        {
            const int need = t - 7;
            while (!__all(pl >= need))
                pl = (lane < 16)
                   ? __hip_atomic_load(&progress[i * 16 + lane], __ATOMIC_RELAXED,
                                       __HIP_MEMORY_SCOPE_AGENT)
                   : 0x7fffffff;
        }

        // gates + cell update (fp32), 2 adjacent cols per thread
        float xi0 = S_lds[0][s][2 * cp]     + ax0.x;
        float xi1 = S_lds[0][s][2 * cp + 1] + ax0.y;
        float xf0 = S_lds[1][s][2 * cp]     + ax1.x;
        float xf1 = S_lds[1][s][2 * cp + 1] + ax1.y;
        float xo0 = S_lds[2][s][2 * cp]     + ax2.x;
        float xo1 = S_lds[2][s][2 * cp + 1] + ax2.y;
        float xg0 = S_lds[3][s][2 * cp]     + ax3.x;
        float xg1 = S_lds[3][s][2 * cp + 1] + ax3.y;

        float i0 = sigmoidf_(xi0), f0 = sigmoidf_(xf0), o0 = sigmoidf_(xo0), g0 = tanhf_(xg0);
        c0 = f0 * c0 + i0 * g0;
        float h0v = o0 * tanhf_(c0);
        float i1 = sigmoidf_(xi1), f1 = sigmoidf_(xf1), o1 = sigmoidf_(xo1), g1 = tanhf_(xg1);
        c1 = f1 * c1 + i1 * g1;
        float h1v = o1 * tanhf_(c1);

        *(f32x2*)(out + ((size_t)seq * TTOT + t) * HID + hc0) = (f32x2){h0v, h1v};

        // publish tagged h_{t+1} chunk (1 u64 RMW per thread, fire-and-forget)
        {
            const u32 tg2 = (u32)(t + 2);
            u32 w0 = ((u32)__builtin_bit_cast(unsigned short, (__bf16)h0v) << 16) | tg2;
            u32 w1 = ((u32)__builtin_bit_cast(unsigned short, (__bf16)h1v) << 16) | tg2;
            u64 pk = (u64)w0 | ((u64)w1 << 32);
            u64* dst = (u64*)(hctag + (size_t)((t + 1) & 7) * 16384)
                     + (size_t)i * 4096 + j * 256 + s * 16 + cp;
            __hip_atomic_exchange(dst, pk, __ATOMIC_RELAXED, __HIP_MEMORY_SCOPE_AGENT);
        }
    }

    cstate[seq * HID + hc0]     = c0;
    cstate[seq * HID + hc0 + 1] = c1;
}

extern "C" void kernel_launch(void* const* d_in, const int* in_sizes, int n_in,
                              void* d_out, int out_size, void* d_ws, size_t ws_size,
                              hipStream_t stream)
{
    const float* x  = (const float*)d_in[0];
    const float* h0 = (const float*)d_in[1];
    const float* Wx = (const float*)d_in[2];
    const float* Wh = (const float*)d_in[3];
    const float* b  = (const float*)d_in[4];
    float* out = (float*)d_out;

    char* ws = (char*)d_ws;
    __bf16* WxbT   = (__bf16*)(ws);                                // 2 MB
    __bf16* WhbT   = (__bf16*)(ws + (2u << 20));                   // 2 MB
    u32*    hctag  = (u32*)(ws + (4u << 20));                      // 512 KB (8 slots)
    float*  cstate = (float*)(ws + (4u << 20) + (512u << 10));     // 64 KB
    int*    progress = (int*)(ws + (4u << 20) + (576u << 10));     // 128 B
    float*  Axw    = (float*)(ws + (4u << 20) + (640u << 10));
    const size_t base = (4u << 20) + (640u << 10);

    // largest chunk Tc in {2048,...,16} whose A-buffer fits in ws
    int ltc = 11;
    while (ltc > 4 && base + (((size_t)NSEQ << ltc) * G4 * sizeof(float)) > ws_size) --ltc;
    const int Tc = 1 << ltc;

    lstm_init<<<dim3((G4 * DIM) / 256), dim3(256), 0, stream>>>(
        Wx, Wh, h0, WxbT, WhbT, hctag, cstate, progress);

    for (int t0 = 0; t0 < TTOT; t0 += Tc) {
        gemm_xwx<<<dim3(G4 / 128, (NSEQ << ltc) / 128), dim3(256), 0, stream>>>(
            x, WxbT, b, Axw, t0, ltc);
        lstm_rec<<<dim3(32), dim3(256), 0, stream>>>(
            Axw, WhbT, hctag, cstate, progress, out, t0, Tc);
    }
}

// Round 4
// 12166.094 us; speedup vs baseline: 2.7001x; 2.7001x over previous
//
#include <hip/hip_runtime.h>

typedef __attribute__((ext_vector_type(8))) __bf16 bf16x8;
typedef __attribute__((ext_vector_type(4))) float f32x4;
typedef __attribute__((ext_vector_type(2))) float f32x2;
typedef unsigned int u32;
typedef unsigned long long u64;

#define NSEQ 32
#define TTOT 2048
#define DIM  512
#define HID  512
#define G4   2048   // 4*H
#define TAGM 0x0000ffff0000ffffull

__device__ __forceinline__ float sigmoidf_(float x) {
    return 1.0f / (1.0f + __expf(-x));
}
__device__ __forceinline__ float tanhf_(float x) {
    return 2.0f / (1.0f + __expf(-2.0f * x)) - 1.0f;
}

// comm ring hctag: [8 slots][2 seq-groups][16 chunks][16 seq][16 colpair] u64
//   u64 = (tagged u32 col 2cp+1) << 32 | (tagged u32 col 2cp); tagged = bf16<<16 | (t+1)
// slot stride 8192 u64, group stride 4096 u64, chunk stride 256 u64.

// ---------------- init ----------------
__global__ void lstm_init(const float* __restrict__ Wx, const float* __restrict__ Wh,
                          const float* __restrict__ h0,
                          __bf16* __restrict__ WxbT, __bf16* __restrict__ WhbT,
                          u32* __restrict__ hctag, float* __restrict__ cstate,
                          int* __restrict__ progress)
{
    int idx = blockIdx.x * 256 + threadIdx.x;   // 0 .. 2048*512-1
    int c = idx & (G4 - 1);
    int k = idx >> 11;
    WxbT[(size_t)c * DIM + k] = (__bf16)Wx[idx];
    WhbT[(size_t)c * HID + k] = (__bf16)Wh[idx];
    if (idx < 8 * 16384) {                      // scrub all 8 ring slots
        u32 v = 0;
        if ((idx >> 14) == 0) {                 // seed slot 0 = h_0, tag 1
            int f  = idx >> 1;                  // u64 index within slot
            int i  = f >> 12;
            int j  = (f >> 8) & 15;
            int s  = (f >> 4) & 15;
            int cp = f & 15;
            int seq = i * 16 + s;
            int col = j * 32 + cp * 2 + (idx & 1);
            __bf16 hb = (__bf16)h0[seq * HID + col];
            v = ((u32)__builtin_bit_cast(unsigned short, hb) << 16) | 1u;
        }
        hctag[idx] = v;
    }
    if (idx < NSEQ * HID) cstate[idx] = 0.0f;
    if (idx < 32) progress[idx] = -1;
}

// ---------------- stage 1: A = x @ Wx + b (unchanged) ----------------
__global__ __launch_bounds__(256) void gemm_xwx(
    const float* __restrict__ x, const __bf16* __restrict__ WxbT,
    const float* __restrict__ b, float* __restrict__ Axw, int t0, int ltc)
{
    const int Tc   = 1 << ltc;
    const int cb   = blockIdx.x * 128;
    const int m0   = blockIdx.y * 128;
    const int tid  = threadIdx.x;
    const int w    = tid >> 6;
    const int lane = tid & 63;
    const int l15  = lane & 15;
    const int lq   = lane >> 4;
    const int wm   = w >> 1, wn = w & 1;

    f32x4 acc[4][4] = {};

    const float* xrow[4];
#pragma unroll
    for (int mi = 0; mi < 4; ++mi) {
        int r  = m0 + wm * 64 + mi * 16 + l15;
        int n  = r >> ltc;
        int tl = r & (Tc - 1);
        xrow[mi] = x + ((size_t)n * TTOT + (t0 + tl)) * DIM;
    }
    const __bf16* bcol[4];
#pragma unroll
    for (int ni = 0; ni < 4; ++ni)
        bcol[ni] = WxbT + (size_t)(cb + wn * 64 + ni * 16 + l15) * DIM;

    for (int k0 = 0; k0 < DIM; k0 += 32) {
        bf16x8 af[4], bfr[4];
#pragma unroll
        for (int mi = 0; mi < 4; ++mi) {
            const float* p = xrow[mi] + k0 + lq * 8;
            f32x4 f0 = *(const f32x4*)p;
            f32x4 f1 = *(const f32x4*)(p + 4);
            bf16x8 a;
            a[0] = (__bf16)f0[0]; a[1] = (__bf16)f0[1]; a[2] = (__bf16)f0[2]; a[3] = (__bf16)f0[3];
            a[4] = (__bf16)f1[0]; a[5] = (__bf16)f1[1]; a[6] = (__bf16)f1[2]; a[7] = (__bf16)f1[3];
            af[mi] = a;
        }
#pragma unroll
        for (int ni = 0; ni < 4; ++ni)
            bfr[ni] = *(const bf16x8*)(bcol[ni] + k0 + lq * 8);
#pragma unroll
        for (int mi = 0; mi < 4; ++mi)
#pragma unroll
            for (int ni = 0; ni < 4; ++ni)
                acc[mi][ni] = __builtin_amdgcn_mfma_f32_16x16x32_bf16(af[mi], bfr[ni], acc[mi][ni], 0, 0, 0);
    }

#pragma unroll
    for (int ni = 0; ni < 4; ++ni) {
        int col = cb + wn * 64 + ni * 16 + l15;
        float bias = b[col];
#pragma unroll
        for (int mi = 0; mi < 4; ++mi) {
#pragma unroll
            for (int j = 0; j < 4; ++j) {
                int r  = m0 + wm * 64 + mi * 16 + lq * 4 + j;
                int n  = r >> ltc;
                int tl = r & (Tc - 1);
                Axw[((size_t)n * Tc + tl) * G4 + col] = acc[mi][ni][j] + bias;
            }
        }
    }
}

// ---------------- stage 2: 2x16 partition, cooperative row poll + LDS staging ----------------
// WG g = (i = g>>4 seq-group of 16, j = g&15 h-col chunk of 32).
// Wave w: gate quadrant w, 32 cols = 2 N-tiles, M-tile = the 16 seqs. bfrag = 128 VGPR.
// Poll: 16 u64/thread cooperative (32 VGPR), per-index retry, sched_barrier pins issue.
__global__ __launch_bounds__(256, 1) void lstm_rec(
    const float* __restrict__ Axw,    // [32][Tc][2048]
    const __bf16* __restrict__ WhbT,  // [2048][512]
    u32* __restrict__ hctag,          // ring
    float* __restrict__ cstate,       // [32][512]
    int* __restrict__ progress,       // [32]
    float* __restrict__ out,          // [32][2048][512]
    int t0, int Tc)
{
    const int g    = blockIdx.x;
    const int i    = g >> 4;
    const int j    = g & 15;
    const int tid  = threadIdx.x;
    const int w    = tid >> 6;
    const int lane = tid & 63;
    const int l15  = lane & 15;
    const int lq   = lane >> 4;

    // persistent Wh B-fragments: quadrant w, cols j*32 + [0,32), 2 N-tiles x 16 K-tiles
    bf16x8 bfrag[2][16];
#pragma unroll
    for (int n = 0; n < 2; ++n) {
        const __bf16* base = WhbT + (size_t)(w * 512 + j * 32 + n * 16 + l15) * HID + lq * 8;
#pragma unroll
        for (int kt = 0; kt < 16; ++kt)
            bfrag[n][kt] = *(const bf16x8*)(base + kt * 32);
    }
    // keep-alive: make fragments opaque so the compiler cannot rematerialize from memory
#pragma unroll
    for (int n = 0; n < 2; ++n)
#pragma unroll
        for (int kt = 0; kt < 16; ++kt)
            asm volatile("" : "+v"(bfrag[n][kt]));

    // gates-phase mapping
    const int s   = tid >> 4;         // seq within group
    const int cp  = tid & 15;         // col-pair within chunk
    const int seq = i * 16 + s;
    const int hc0 = j * 32 + 2 * cp;
    float c0 = cstate[seq * HID + hc0];
    float c1 = cstate[seq * HID + hc0 + 1];

    __shared__ __align__(16) unsigned char hs[16 * 1024];  // [16 seq][512 col] bf16, XOR-swizzled
    __shared__ float S_lds[4][16][34];

    for (int t = t0; t < t0 + Tc; ++t) {
        // flow-control probe (steady state: already satisfied; consumed before publish)
        int pl = (lane < 16)
               ? __hip_atomic_load(&progress[i * 16 + lane], __ATOMIC_RELAXED,
                                   __HIP_MEMORY_SCOPE_AGENT)
               : 0x7fffffff;

        // Axw prefetch (latency hidden under the poll)
        const float* Ap = Axw + ((size_t)seq * Tc + (t - t0)) * G4 + hc0;
        f32x2 ax0 = *(const f32x2*)(Ap);
        f32x2 ax1 = *(const f32x2*)(Ap + 512);
        f32x2 ax2 = *(const f32x2*)(Ap + 1024);
        f32x2 ax3 = *(const f32x2*)(Ap + 1536);

        // ---- cooperative tagged poll of this row: 16 u64/thread, all issued up-front ----
        const u64* hbase = (const u64*)hctag + (size_t)(t & 7) * 8192 + (size_t)i * 4096;
        const u32 etag = (u32)(t + 1);
        const u64 pat  = (u64)etag | ((u64)etag << 32);

        u64 va[16];
#pragma unroll
        for (int n = 0; n < 16; ++n)
            va[n] = __hip_atomic_load(hbase + n * 256 + tid, __ATOMIC_RELAXED,
                                      __HIP_MEMORY_SCOPE_AGENT);
        __builtin_amdgcn_sched_barrier(0);   // pin: all 16 loads in flight before checks
#pragma unroll
        for (int n = 0; n < 16; ++n) {
            while (!__all(((va[n] ^ pat) & TAGM) == 0ull))
                va[n] = __hip_atomic_load(hbase + n * 256 + tid, __ATOMIC_RELAXED,
                                          __HIP_MEMORY_SCOPE_AGENT);
        }

        // strip tags -> swizzled LDS. load n = (chunk n, seq s, colpair cp): row s, byte n*64+cp*4
#pragma unroll
        for (int n = 0; n < 16; ++n) {
            u32 packed = ((u32)(va[n] >> 16) & 0xffffu) | ((u32)(va[n] >> 32) & 0xffff0000u);
            *(u32*)(hs + ((s * 1024 + n * 64 + cp * 4) ^ ((s & 7) << 4))) = packed;
        }
        __syncthreads();

        // whole WG holds h_t -> release the slot
        if (tid == 0)
            __hip_atomic_exchange(&progress[g], t, __ATOMIC_RELAXED, __HIP_MEMORY_SCOPE_AGENT);

        // ---- S = h_t @ Wh_slice: 16 K-tiles, A from LDS, B resident ----
        f32x4 acc0 = {0, 0, 0, 0}, acc1 = {0, 0, 0, 0};
        const int xr = (l15 & 7) << 4;
#pragma unroll
        for (int kt = 0; kt < 16; ++kt) {
            bf16x8 a = *(const bf16x8*)(hs + ((l15 * 1024 + kt * 64 + lq * 16) ^ xr));
            acc0 = __builtin_amdgcn_mfma_f32_16x16x32_bf16(a, bfrag[0][kt], acc0, 0, 0, 0);
            acc1 = __builtin_amdgcn_mfma_f32_16x16x32_bf16(a, bfrag[1][kt], acc1, 0, 0, 0);
        }

        // cross-wave gate exchange (C/D: col=l15, row=lq*4+jj; rows are seqs)
#pragma unroll
        for (int jj = 0; jj < 4; ++jj) {
            S_lds[w][lq * 4 + jj][l15]      = acc0[jj];
            S_lds[w][lq * 4 + jj][16 + l15] = acc1[jj];
        }
        __syncthreads();

        // ---- gates + cell update (fp32), 2 adjacent cols/thread ----
        f32x2 si = *(const f32x2*)&S_lds[0][s][2 * cp];
        f32x2 sf = *(const f32x2*)&S_lds[1][s][2 * cp];
        f32x2 so = *(const f32x2*)&S_lds[2][s][2 * cp];
        f32x2 sg = *(const f32x2*)&S_lds[3][s][2 * cp];

        float i0 = sigmoidf_(si.x + ax0.x), f0 = sigmoidf_(sf.x + ax1.x);
        float o0 = sigmoidf_(so.x + ax2.x), g0 = tanhf_(sg.x + ax3.x);
        c0 = f0 * c0 + i0 * g0;
        float h0v = o0 * tanhf_(c0);
        float i1 = sigmoidf_(si.y + ax0.y), f1 = sigmoidf_(sf.y + ax1.y);
        float o1 = sigmoidf_(so.y + ax2.y), g1 = tanhf_(sg.y + ax3.y);
        c1 = f1 * c1 + i1 * g1;
        float h1v = o1 * tanhf_(c1);

        *(f32x2*)(out + ((size_t)seq * TTOT + t) * HID + hc0) = (f32x2){h0v, h1v};

        // ring flow control: slot (t+1)&7 currently holds h_{t-7}
        {
            const int need = t - 7;
            while (!__all(pl >= need))
                pl = (lane < 16)
                   ? __hip_atomic_load(&progress[i * 16 + lane], __ATOMIC_RELAXED,
                                       __HIP_MEMORY_SCOPE_AGENT)
                   : 0x7fffffff;
        }

        // publish tagged h_{t+1} (1 u64 RMW/thread at the coherence point)
        {
            const u32 tg2 = (u32)(t + 2);
            u32 w0 = ((u32)__builtin_bit_cast(unsigned short, (__bf16)h0v) << 16) | tg2;
            u32 w1 = ((u32)__builtin_bit_cast(unsigned short, (__bf16)h1v) << 16) | tg2;
            u64 pk = (u64)w0 | ((u64)w1 << 32);
            u64* dst = (u64*)hctag + (size_t)((t + 1) & 7) * 8192
                     + (size_t)i * 4096 + j * 256 + s * 16 + cp;
            __hip_atomic_exchange(dst, pk, __ATOMIC_RELAXED, __HIP_MEMORY_SCOPE_AGENT);
        }
    }

    cstate[seq * HID + hc0]     = c0;
    cstate[seq * HID + hc0 + 1] = c1;
}

extern "C" void kernel_launch(void* const* d_in, const int* in_sizes, int n_in,
                              void* d_out, int out_size, void* d_ws, size_t ws_size,
                              hipStream_t stream)
{
    const float* x  = (const float*)d_in[0];
    const float* h0 = (const float*)d_in[1];
    const float* Wx = (const float*)d_in[2];
    const float* Wh = (const float*)d_in[3];
    const float* b  = (const float*)d_in[4];
    float* out = (float*)d_out;

    char* ws = (char*)d_ws;
    __bf16* WxbT   = (__bf16*)(ws);                                // 2 MB
    __bf16* WhbT   = (__bf16*)(ws + (2u << 20));                   // 2 MB
    u32*    hctag  = (u32*)(ws + (4u << 20));                      // 512 KB (8 slots)
    float*  cstate = (float*)(ws + (4u << 20) + (512u << 10));     // 64 KB
    int*    progress = (int*)(ws + (4u << 20) + (576u << 10));     // 128 B
    float*  Axw    = (float*)(ws + (4u << 20) + (640u << 10));
    const size_t base = (4u << 20) + (640u << 10);

    // largest chunk Tc in {2048,...,16} whose A-buffer fits in ws
    int ltc = 11;
    while (ltc > 4 && base + (((size_t)NSEQ << ltc) * G4 * sizeof(float)) > ws_size) --ltc;
    const int Tc = 1 << ltc;

    lstm_init<<<dim3((G4 * DIM) / 256), dim3(256), 0, stream>>>(
        Wx, Wh, h0, WxbT, WhbT, hctag, cstate, progress);

    for (int t0 = 0; t0 < TTOT; t0 += Tc) {
        gemm_xwx<<<dim3(G4 / 128, (NSEQ << ltc) / 128), dim3(256), 0, stream>>>(
            x, WxbT, b, Axw, t0, ltc);
        lstm_rec<<<dim3(32), dim3(256), 0, stream>>>(
            Axw, WhbT, hctag, cstate, progress, out, t0, Tc);
    }
}

// Round 5
// 9424.299 us; speedup vs baseline: 3.4856x; 1.2909x over previous
//
#include <hip/hip_runtime.h>

typedef __attribute__((ext_vector_type(8))) __bf16 bf16x8;
typedef __attribute__((ext_vector_type(4))) float f32x4;
typedef __attribute__((ext_vector_type(2))) float f32x2;
typedef __attribute__((ext_vector_type(4))) unsigned int u32x4;
typedef unsigned int u32;
typedef unsigned long long u64;

#define NSEQ 32
#define TTOT 2048
#define DIM  512
#define HID  512
#define G4   2048   // 4*H
#define TAGM 0x0000ffff0000ffffull

__device__ __forceinline__ float sigmoidf_(float x) {
    return 1.0f / (1.0f + __expf(-x));
}
__device__ __forceinline__ float tanhf_(float x) {
    return 2.0f / (1.0f + __expf(-2.0f * x)) - 1.0f;
}

// comm ring hctag: [8 slots][2 seq-groups][16 chunks][16 seq][16 colpair] u64
//   u64 = (tagged u32 col 2cp+1) << 32 | (tagged u32 col 2cp); tagged = bf16<<16 | (t+1)
// slot stride 8192 u64. Tag monotonicity makes the ring self-flow-controlled:
// entering step t+1 requires observing everyone's step-t publish => lag <= 1 step;
// slot overwrite at distance 8 is provably safe. NO progress array, NO fences.

// ---------------- init ----------------
__global__ void lstm_init(const float* __restrict__ Wx, const float* __restrict__ Wh,
                          const float* __restrict__ h0,
                          __bf16* __restrict__ WxbT, __bf16* __restrict__ WhbT,
                          u32* __restrict__ hctag, float* __restrict__ cstate)
{
    int idx = blockIdx.x * 256 + threadIdx.x;   // 0 .. 2048*512-1
    int c = idx & (G4 - 1);
    int k = idx >> 11;
    WxbT[(size_t)c * DIM + k] = (__bf16)Wx[idx];
    WhbT[(size_t)c * HID + k] = (__bf16)Wh[idx];
    if (idx < 8 * 16384) {                      // scrub all 8 ring slots
        u32 v = 0;
        if ((idx >> 14) == 0) {                 // seed slot 0 = h_0, tag 1
            int f  = idx >> 1;                  // u64 index within slot
            int i  = f >> 12;
            int j  = (f >> 8) & 15;
            int s  = (f >> 4) & 15;
            int cp = f & 15;
            int seq = i * 16 + s;
            int col = j * 32 + cp * 2 + (idx & 1);
            __bf16 hb = (__bf16)h0[seq * HID + col];
            v = ((u32)__builtin_bit_cast(unsigned short, hb) << 16) | 1u;
        }
        hctag[idx] = v;
    }
    if (idx < NSEQ * HID) cstate[idx] = 0.0f;
}

// ---------------- stage 1: A = x @ Wx + b (unchanged) ----------------
__global__ __launch_bounds__(256) void gemm_xwx(
    const float* __restrict__ x, const __bf16* __restrict__ WxbT,
    const float* __restrict__ b, float* __restrict__ Axw, int t0, int ltc)
{
    const int Tc   = 1 << ltc;
    const int cb   = blockIdx.x * 128;
    const int m0   = blockIdx.y * 128;
    const int tid  = threadIdx.x;
    const int w    = tid >> 6;
    const int lane = tid & 63;
    const int l15  = lane & 15;
    const int lq   = lane >> 4;
    const int wm   = w >> 1, wn = w & 1;

    f32x4 acc[4][4] = {};

    const float* xrow[4];
#pragma unroll
    for (int mi = 0; mi < 4; ++mi) {
        int r  = m0 + wm * 64 + mi * 16 + l15;
        int n  = r >> ltc;
        int tl = r & (Tc - 1);
        xrow[mi] = x + ((size_t)n * TTOT + (t0 + tl)) * DIM;
    }
    const __bf16* bcol[4];
#pragma unroll
    for (int ni = 0; ni < 4; ++ni)
        bcol[ni] = WxbT + (size_t)(cb + wn * 64 + ni * 16 + l15) * DIM;

    for (int k0 = 0; k0 < DIM; k0 += 32) {
        bf16x8 af[4], bfr[4];
#pragma unroll
        for (int mi = 0; mi < 4; ++mi) {
            const float* p = xrow[mi] + k0 + lq * 8;
            f32x4 f0 = *(const f32x4*)p;
            f32x4 f1 = *(const f32x4*)(p + 4);
            bf16x8 a;
            a[0] = (__bf16)f0[0]; a[1] = (__bf16)f0[1]; a[2] = (__bf16)f0[2]; a[3] = (__bf16)f0[3];
            a[4] = (__bf16)f1[0]; a[5] = (__bf16)f1[1]; a[6] = (__bf16)f1[2]; a[7] = (__bf16)f1[3];
            af[mi] = a;
        }
#pragma unroll
        for (int ni = 0; ni < 4; ++ni)
            bfr[ni] = *(const bf16x8*)(bcol[ni] + k0 + lq * 8);
#pragma unroll
        for (int mi = 0; mi < 4; ++mi)
#pragma unroll
            for (int ni = 0; ni < 4; ++ni)
                acc[mi][ni] = __builtin_amdgcn_mfma_f32_16x16x32_bf16(af[mi], bfr[ni], acc[mi][ni], 0, 0, 0);
    }

#pragma unroll
    for (int ni = 0; ni < 4; ++ni) {
        int col = cb + wn * 64 + ni * 16 + l15;
        float bias = b[col];
#pragma unroll
        for (int mi = 0; mi < 4; ++mi) {
#pragma unroll
            for (int j = 0; j < 4; ++j) {
                int r  = m0 + wm * 64 + mi * 16 + lq * 4 + j;
                int n  = r >> ltc;
                int tl = r & (Tc - 1);
                Axw[((size_t)n * Tc + tl) * G4 + col] = acc[mi][ni][j] + bias;
            }
        }
    }
}

// ---------------- stage 2: 2x16 partition, K-split waves, poll = A-frags ----------------
// WG g = (i = g>>4 seq-group, j = g&15 h-col chunk). Wave w owns K-tiles/chunks
// 4w..4w+3 for ALL 8 N-tiles (WG's 128 gate cols). The 16 polled u64/thread ARE the
// wave's A-fragments (strip tags in-register, MFMA directly; no h staging).
// Cross-wave K-reduction via ping-pong LDS partials; 1 syncthreads/step, 0 fences.
__global__ __launch_bounds__(256, 1) void lstm_rec(
    const float* __restrict__ Axw,    // [32][Tc][2048]
    const __bf16* __restrict__ WhbT,  // [2048][512]
    u32* __restrict__ hctag,          // ring
    float* __restrict__ cstate,       // [32][512]
    float* __restrict__ out,          // [32][2048][512]
    int t0, int Tc)
{
    const int g    = blockIdx.x;
    const int i    = g >> 4;
    const int j    = g & 15;
    const int tid  = threadIdx.x;
    const int w    = tid >> 6;
    const int lane = tid & 63;
    const int l15  = lane & 15;
    const int lq   = lane >> 4;

    // B-frags: 8 N-tiles x 4 K-tiles (K-tile = 4w+kk). col(n) = (n>>1)*512 + j*32 + (n&1)*16 + l15
    bf16x8 bfrag[8][4];
#pragma unroll
    for (int n = 0; n < 8; ++n) {
        const __bf16* base = WhbT
            + (size_t)((n >> 1) * 512 + j * 32 + (n & 1) * 16 + l15) * HID
            + (4 * w) * 32 + lq * 8;
#pragma unroll
        for (int kk = 0; kk < 4; ++kk)
            bfrag[n][kk] = *(const bf16x8*)(base + kk * 32);
    }
#pragma unroll
    for (int n = 0; n < 8; ++n)
#pragma unroll
        for (int kk = 0; kk < 4; ++kk)
            asm volatile("" : "+v"(bfrag[n][kk]));   // no remat

    // gate-phase mapping
    const int s   = tid >> 4;
    const int cp  = tid & 15;
    const int seq = i * 16 + s;
    const int hc0 = j * 32 + 2 * cp;
    float c0 = cstate[seq * HID + hc0];
    float c1 = cstate[seq * HID + hc0 + 1];

    __shared__ float P[2][4][16][132];   // [parity][wave][seq][128 gate-cols local]

    for (int t = t0; t < t0 + Tc; ++t) {
        // Axw prefetch (hidden under poll)
        const float* Ap = Axw + ((size_t)seq * Tc + (t - t0)) * G4 + hc0;
        f32x2 ax0 = *(const f32x2*)(Ap);
        f32x2 ax1 = *(const f32x2*)(Ap + 512);
        f32x2 ax2 = *(const f32x2*)(Ap + 1024);
        f32x2 ax3 = *(const f32x2*)(Ap + 1536);

        const u64* hbase = (const u64*)hctag + (size_t)(t & 7) * 8192 + (size_t)i * 4096;
        const u32 etag = (u32)(t + 1);
        const u64 pat  = (u64)etag | ((u64)etag << 32);

        // issue all 16 A-loads (4 chunks x 4 u64); per-thread addr = own A-fragment
        u64 va[4][4];
#pragma unroll
        for (int kk = 0; kk < 4; ++kk) {
            const u64* cb = hbase + (size_t)(4 * w + kk) * 256 + l15 * 16 + lq * 4;
#pragma unroll
            for (int e = 0; e < 4; ++e)
                va[kk][e] = __hip_atomic_load(cb + e, __ATOMIC_RELAXED,
                                              __HIP_MEMORY_SCOPE_AGENT);
        }
        __builtin_amdgcn_sched_barrier(0);

        f32x4 acc[8] = {};
#pragma unroll
        for (int kk = 0; kk < 4; ++kk) {
            const u64* cb = hbase + (size_t)(4 * w + kk) * 256 + l15 * 16 + lq * 4;
            bool ok = (((va[kk][0] ^ pat) & TAGM) == 0ull) &&
                      (((va[kk][1] ^ pat) & TAGM) == 0ull) &&
                      (((va[kk][2] ^ pat) & TAGM) == 0ull) &&
                      (((va[kk][3] ^ pat) & TAGM) == 0ull);
            while (!__all(ok)) {
#pragma unroll
                for (int e = 0; e < 4; ++e)
                    va[kk][e] = __hip_atomic_load(cb + e, __ATOMIC_RELAXED,
                                                  __HIP_MEMORY_SCOPE_AGENT);
                ok = (((va[kk][0] ^ pat) & TAGM) == 0ull) &&
                     (((va[kk][1] ^ pat) & TAGM) == 0ull) &&
                     (((va[kk][2] ^ pat) & TAGM) == 0ull) &&
                     (((va[kk][3] ^ pat) & TAGM) == 0ull);
            }
            // strip tags -> A-frag (8 bf16 = k cols 8lq..8lq+7 of K-tile 4w+kk)
            u32 q0 = ((u32)(va[kk][0] >> 16) & 0xffffu) | ((u32)(va[kk][0] >> 32) & 0xffff0000u);
            u32 q1 = ((u32)(va[kk][1] >> 16) & 0xffffu) | ((u32)(va[kk][1] >> 32) & 0xffff0000u);
            u32 q2 = ((u32)(va[kk][2] >> 16) & 0xffffu) | ((u32)(va[kk][2] >> 32) & 0xffff0000u);
            u32 q3 = ((u32)(va[kk][3] >> 16) & 0xffffu) | ((u32)(va[kk][3] >> 32) & 0xffff0000u);
            bf16x8 a = __builtin_bit_cast(bf16x8, (u32x4){q0, q1, q2, q3});
#pragma unroll
            for (int n = 0; n < 8; ++n)
                acc[n] = __builtin_amdgcn_mfma_f32_16x16x32_bf16(a, bfrag[n][kk], acc[n], 0, 0, 0);
        }

        // write K-partials (C/D: row seq = lq*4+jj, col = n*16+l15); ping-pong parity
        const int par = t & 1;
#pragma unroll
        for (int n = 0; n < 8; ++n)
#pragma unroll
            for (int jj = 0; jj < 4; ++jj)
                P[par][w][lq * 4 + jj][n * 16 + l15] = acc[n][jj];
        __syncthreads();

        // gates: sum the 4 wave-partials per quadrant
        f32x2 sq[4];
#pragma unroll
        for (int q = 0; q < 4; ++q) {
            f32x2 v0 = *(const f32x2*)&P[par][0][s][q * 32 + 2 * cp];
            f32x2 v1 = *(const f32x2*)&P[par][1][s][q * 32 + 2 * cp];
            f32x2 v2 = *(const f32x2*)&P[par][2][s][q * 32 + 2 * cp];
            f32x2 v3 = *(const f32x2*)&P[par][3][s][q * 32 + 2 * cp];
            sq[q].x = (v0.x + v1.x) + (v2.x + v3.x);
            sq[q].y = (v0.y + v1.y) + (v2.y + v3.y);
        }

        float i0 = sigmoidf_(sq[0].x + ax0.x), f0 = sigmoidf_(sq[1].x + ax1.x);
        float o0 = sigmoidf_(sq[2].x + ax2.x), g0 = tanhf_(sq[3].x + ax3.x);
        c0 = f0 * c0 + i0 * g0;
        float h0v = o0 * tanhf_(c0);
        float i1 = sigmoidf_(sq[0].y + ax0.y), f1 = sigmoidf_(sq[1].y + ax1.y);
        float o1 = sigmoidf_(sq[2].y + ax2.y), g1 = tanhf_(sq[3].y + ax3.y);
        c1 = f1 * c1 + i1 * g1;
        float h1v = o1 * tanhf_(c1);

        *(f32x2*)(out + ((size_t)seq * TTOT + t) * HID + hc0) = (f32x2){h0v, h1v};

        // publish tagged h_{t+1} (1 u64 RMW/thread at the coherence point)
        {
            const u32 tg2 = (u32)(t + 2);
            u32 w0 = ((u32)__builtin_bit_cast(unsigned short, (__bf16)h0v) << 16) | tg2;
            u32 w1 = ((u32)__builtin_bit_cast(unsigned short, (__bf16)h1v) << 16) | tg2;
            u64 pk = (u64)w0 | ((u64)w1 << 32);
            u64* dst = (u64*)hctag + (size_t)((t + 1) & 7) * 8192
                     + (size_t)i * 4096 + j * 256 + s * 16 + cp;
            __hip_atomic_exchange(dst, pk, __ATOMIC_RELAXED, __HIP_MEMORY_SCOPE_AGENT);
        }
        asm volatile("" ::: "memory");   // pin publish before next step's polls
    }

    cstate[seq * HID + hc0]     = c0;
    cstate[seq * HID + hc0 + 1] = c1;
}

extern "C" void kernel_launch(void* const* d_in, const int* in_sizes, int n_in,
                              void* d_out, int out_size, void* d_ws, size_t ws_size,
                              hipStream_t stream)
{
    const float* x  = (const float*)d_in[0];
    const float* h0 = (const float*)d_in[1];
    const float* Wx = (const float*)d_in[2];
    const float* Wh = (const float*)d_in[3];
    const float* b  = (const float*)d_in[4];
    float* out = (float*)d_out;

    char* ws = (char*)d_ws;
    __bf16* WxbT   = (__bf16*)(ws);                                // 2 MB
    __bf16* WhbT   = (__bf16*)(ws + (2u << 20));                   // 2 MB
    u32*    hctag  = (u32*)(ws + (4u << 20));                      // 512 KB (8 slots)
    float*  cstate = (float*)(ws + (4u << 20) + (512u << 10));     // 64 KB
    float*  Axw    = (float*)(ws + (4u << 20) + (640u << 10));
    const size_t base = (4u << 20) + (640u << 10);

    // largest chunk Tc in {2048,...,16} whose A-buffer fits in ws
    int ltc = 11;
    while (ltc > 4 && base + (((size_t)NSEQ << ltc) * G4 * sizeof(float)) > ws_size) --ltc;
    const int Tc = 1 << ltc;

    lstm_init<<<dim3((G4 * DIM) / 256), dim3(256), 0, stream>>>(
        Wx, Wh, h0, WxbT, WhbT, hctag, cstate);

    for (int t0 = 0; t0 < TTOT; t0 += Tc) {
        gemm_xwx<<<dim3(G4 / 128, (NSEQ << ltc) / 128), dim3(256), 0, stream>>>(
            x, WxbT, b, Axw, t0, ltc);
        lstm_rec<<<dim3(32), dim3(256), 0, stream>>>(
            Axw, WhbT, hctag, cstate, out, t0, Tc);
    }
}

// Round 6
// 6516.766 us; speedup vs baseline: 5.0408x; 1.4462x over previous
//
#include <hip/hip_runtime.h>

typedef __attribute__((ext_vector_type(8))) __bf16 bf16x8;
typedef __attribute__((ext_vector_type(4))) float f32x4;
typedef __attribute__((ext_vector_type(2))) float f32x2;
typedef __attribute__((ext_vector_type(4))) unsigned int u32x4;
typedef unsigned int u32;
typedef unsigned long long u64;

#define NSEQ 32
#define TTOT 2048
#define DIM  512
#define HID  512
#define G4   2048   // 4*H

__device__ __forceinline__ float sigmoidf_(float x) {
    return 1.0f / (1.0f + __expf(-x));
}
__device__ __forceinline__ float tanhf_(float x) {
    return 2.0f / (1.0f + __expf(-2.0f * x)) - 1.0f;
}

// comm ring hcomm (clean bf16, no tags): [8 slots][2 grp][16 chunk][16 seq][32 col]
//   slot stride 16384 bf16 (32 KB), grp stride 8192, chunk stride 512, seq stride 32.
// sentinels sent[2][16] u32: sent[i][j] = T  <=>  WG (i,j) has published h_T into
//   slot T&7 and ALL its data stores were ACKed at the coherence point before the
//   sentinel was issued (enforced by __syncthreads vmcnt-drain). Consumers at step t
//   spin on sent[i][*] >= t (one 64B line), then bulk-read the 16KB row once.
// Self-flow-control: entering step t requires observing everyone's h_t publish =>
//   global skew <= 1 step => ring-8 overwrite provably safe. No fences anywhere.

// ---------------- init ----------------
__global__ void lstm_init(const float* __restrict__ Wx, const float* __restrict__ Wh,
                          const float* __restrict__ h0,
                          __bf16* __restrict__ WxbT, __bf16* __restrict__ WhbT,
                          __bf16* __restrict__ hcomm, u32* __restrict__ sent,
                          float* __restrict__ cstate)
{
    int idx = blockIdx.x * 256 + threadIdx.x;   // 0 .. 2048*512-1
    int c = idx & (G4 - 1);
    int k = idx >> 11;
    WxbT[(size_t)c * DIM + k] = (__bf16)Wx[idx];
    WhbT[(size_t)c * HID + k] = (__bf16)Wh[idx];
    if (idx < NSEQ * HID) {                     // seed slot 0 = h_0
        int seq = idx >> 9, cc = idx & 511;
        int i = seq >> 4, s = seq & 15;
        hcomm[(size_t)i * 8192 + (cc >> 5) * 512 + s * 32 + (cc & 31)] = (__bf16)h0[idx];
        cstate[idx] = 0.0f;
    }
    if (idx < 32) sent[idx] = 0;                // "h_0 ready" (reset every launch/replay)
}

// ---------------- stage 1: A = x @ Wx + b (unchanged) ----------------
__global__ __launch_bounds__(256) void gemm_xwx(
    const float* __restrict__ x, const __bf16* __restrict__ WxbT,
    const float* __restrict__ b, float* __restrict__ Axw, int t0, int ltc)
{
    const int Tc   = 1 << ltc;
    const int cb   = blockIdx.x * 128;
    const int m0   = blockIdx.y * 128;
    const int tid  = threadIdx.x;
    const int w    = tid >> 6;
    const int lane = tid & 63;
    const int l15  = lane & 15;
    const int lq   = lane >> 4;
    const int wm   = w >> 1, wn = w & 1;

    f32x4 acc[4][4] = {};

    const float* xrow[4];
#pragma unroll
    for (int mi = 0; mi < 4; ++mi) {
        int r  = m0 + wm * 64 + mi * 16 + l15;
        int n  = r >> ltc;
        int tl = r & (Tc - 1);
        xrow[mi] = x + ((size_t)n * TTOT + (t0 + tl)) * DIM;
    }
    const __bf16* bcol[4];
#pragma unroll
    for (int ni = 0; ni < 4; ++ni)
        bcol[ni] = WxbT + (size_t)(cb + wn * 64 + ni * 16 + l15) * DIM;

    for (int k0 = 0; k0 < DIM; k0 += 32) {
        bf16x8 af[4], bfr[4];
#pragma unroll
        for (int mi = 0; mi < 4; ++mi) {
            const float* p = xrow[mi] + k0 + lq * 8;
            f32x4 f0 = *(const f32x4*)p;
            f32x4 f1 = *(const f32x4*)(p + 4);
            bf16x8 a;
            a[0] = (__bf16)f0[0]; a[1] = (__bf16)f0[1]; a[2] = (__bf16)f0[2]; a[3] = (__bf16)f0[3];
            a[4] = (__bf16)f1[0]; a[5] = (__bf16)f1[1]; a[6] = (__bf16)f1[2]; a[7] = (__bf16)f1[3];
            af[mi] = a;
        }
#pragma unroll
        for (int ni = 0; ni < 4; ++ni)
            bfr[ni] = *(const bf16x8*)(bcol[ni] + k0 + lq * 8);
#pragma unroll
        for (int mi = 0; mi < 4; ++mi)
#pragma unroll
            for (int ni = 0; ni < 4; ++ni)
                acc[mi][ni] = __builtin_amdgcn_mfma_f32_16x16x32_bf16(af[mi], bfr[ni], acc[mi][ni], 0, 0, 0);
    }

#pragma unroll
    for (int ni = 0; ni < 4; ++ni) {
        int col = cb + wn * 64 + ni * 16 + l15;
        float bias = b[col];
#pragma unroll
        for (int mi = 0; mi < 4; ++mi) {
#pragma unroll
            for (int j = 0; j < 4; ++j) {
                int r  = m0 + wm * 64 + mi * 16 + lq * 4 + j;
                int n  = r >> ltc;
                int tl = r & (Tc - 1);
                Axw[((size_t)n * Tc + tl) * G4 + col] = acc[mi][ni][j] + bias;
            }
        }
    }
}

// ---------------- stage 2: sentinel-gated recurrence, K-split waves ----------------
__global__ __launch_bounds__(256, 1) void lstm_rec(
    const float* __restrict__ Axw,    // [32][Tc][2048]
    const __bf16* __restrict__ WhbT,  // [2048][512]
    __bf16* __restrict__ hcomm,       // ring (clean bf16)
    u32* __restrict__ sent,           // [2][16]
    float* __restrict__ cstate,       // [32][512]
    float* __restrict__ out,          // [32][2048][512]
    int t0, int Tc)
{
    const int g    = blockIdx.x;
    const int i    = g >> 4;
    const int j    = g & 15;
    const int tid  = threadIdx.x;
    const int w    = tid >> 6;
    const int lane = tid & 63;
    const int l15  = lane & 15;
    const int lq   = lane >> 4;

    // B-frags: 8 N-tiles x 4 K-tiles (wave w owns K-tiles 4w..4w+3)
    bf16x8 bfrag[8][4];
#pragma unroll
    for (int n = 0; n < 8; ++n) {
        const __bf16* base = WhbT
            + (size_t)((n >> 1) * 512 + j * 32 + (n & 1) * 16 + l15) * HID
            + (4 * w) * 32 + lq * 8;
#pragma unroll
        for (int kk = 0; kk < 4; ++kk)
            bfrag[n][kk] = *(const bf16x8*)(base + kk * 32);
    }
#pragma unroll
    for (int n = 0; n < 8; ++n)
#pragma unroll
        for (int kk = 0; kk < 4; ++kk)
            asm volatile("" : "+v"(bfrag[n][kk]));   // no remat

    // gate-phase mapping
    const int s   = tid >> 4;
    const int cp  = tid & 15;
    const int seq = i * 16 + s;
    const int hc0 = j * 32 + 2 * cp;
    float c0 = cstate[seq * HID + hc0];
    float c1 = cstate[seq * HID + hc0 + 1];

    const u32* sent_row = sent + i * 16;

    __shared__ float P[4][16][132];   // [wave][seq][128 local gate cols]

    for (int t = t0; t < t0 + Tc; ++t) {
        // Axw prefetch (hidden under sentinel spin)
        const float* Ap = Axw + ((size_t)seq * Tc + (t - t0)) * G4 + hc0;
        f32x2 ax0 = *(const f32x2*)(Ap);
        f32x2 ax1 = *(const f32x2*)(Ap + 512);
        f32x2 ax2 = *(const f32x2*)(Ap + 1024);
        f32x2 ax3 = *(const f32x2*)(Ap + 1536);

        // ---- sentinel spin: one 64B line per round ----
        {
            int sv;
            do {
                sv = (int)__hip_atomic_load(&sent_row[lane & 15], __ATOMIC_RELAXED,
                                            __HIP_MEMORY_SCOPE_AGENT);
            } while (!__all(sv >= t));
        }
        __builtin_amdgcn_sched_barrier(0);   // data loads must not issue before spin exit

        // ---- bulk row read: 8 u64 bypass loads/thread = the wave's A-frags ----
        const u64* slotr = (const u64*)hcomm + (size_t)(t & 7) * 4096 + (size_t)i * 2048;
        u64 d[4][2];
#pragma unroll
        for (int kk = 0; kk < 4; ++kk) {
            const u64* p = slotr + (size_t)(4 * w + kk) * 128 + l15 * 8 + lq * 2;
            d[kk][0] = __hip_atomic_load(p,     __ATOMIC_RELAXED, __HIP_MEMORY_SCOPE_AGENT);
            d[kk][1] = __hip_atomic_load(p + 1, __ATOMIC_RELAXED, __HIP_MEMORY_SCOPE_AGENT);
        }

        f32x4 acc[8] = {};
#pragma unroll
        for (int kk = 0; kk < 4; ++kk) {
            u32x4 q = { (u32)d[kk][0], (u32)(d[kk][0] >> 32),
                        (u32)d[kk][1], (u32)(d[kk][1] >> 32) };
            bf16x8 a = __builtin_bit_cast(bf16x8, q);
#pragma unroll
            for (int n = 0; n < 8; ++n)
                acc[n] = __builtin_amdgcn_mfma_f32_16x16x32_bf16(a, bfrag[n][kk], acc[n], 0, 0, 0);
        }

        // K-partials to LDS (C/D: row=lq*4+jj, col=n*16+l15)
#pragma unroll
        for (int n = 0; n < 8; ++n)
#pragma unroll
            for (int jj = 0; jj < 4; ++jj)
                P[w][lq * 4 + jj][n * 16 + l15] = acc[n][jj];
        __syncthreads();                                    // sync1

        // gates: sum 4 wave-partials per quadrant
        f32x2 sq[4];
#pragma unroll
        for (int q = 0; q < 4; ++q) {
            f32x2 v0 = *(const f32x2*)&P[0][s][q * 32 + 2 * cp];
            f32x2 v1 = *(const f32x2*)&P[1][s][q * 32 + 2 * cp];
            f32x2 v2 = *(const f32x2*)&P[2][s][q * 32 + 2 * cp];
            f32x2 v3 = *(const f32x2*)&P[3][s][q * 32 + 2 * cp];
            sq[q].x = (v0.x + v1.x) + (v2.x + v3.x);
            sq[q].y = (v0.y + v1.y) + (v2.y + v3.y);
        }

        float i0 = sigmoidf_(sq[0].x + ax0.x), f0 = sigmoidf_(sq[1].x + ax1.x);
        float o0 = sigmoidf_(sq[2].x + ax2.x), g0 = tanhf_(sq[3].x + ax3.x);
        c0 = f0 * c0 + i0 * g0;
        float h0v = o0 * tanhf_(c0);
        float i1 = sigmoidf_(sq[0].y + ax0.y), f1 = sigmoidf_(sq[1].y + ax1.y);
        float o1 = sigmoidf_(sq[2].y + ax2.y), g1 = tanhf_(sq[3].y + ax3.y);
        c1 = f1 * c1 + i1 * g1;
        float h1v = o1 * tanhf_(c1);

        *(f32x2*)(out + ((size_t)seq * TTOT + t) * HID + hc0) = (f32x2){h0v, h1v};

        // publish h_{t+1}: pack 2 cols -> u32, pair lanes -> u64, even lanes store (RMW)
        {
            u32 v01 = (u32)__builtin_bit_cast(unsigned short, (__bf16)h0v)
                    | ((u32)__builtin_bit_cast(unsigned short, (__bf16)h1v) << 16);
            u32 partner = (u32)__shfl_xor((int)v01, 1);
            if (!(cp & 1)) {
                u64 pk = (u64)v01 | ((u64)partner << 32);
                u64* dst = (u64*)hcomm + (size_t)((t + 1) & 7) * 4096
                         + (size_t)i * 2048 + (size_t)j * 128 + s * 8 + (cp >> 1);
                __hip_atomic_exchange(dst, pk, __ATOMIC_RELAXED, __HIP_MEMORY_SCOPE_AGENT);
            }
        }
        __syncthreads();                                    // sync2: drains ALL vmcnt
        // all data stores ACKed at coherence point -> sentinel may fly (relaxed)
        if (tid == 0)
            __hip_atomic_exchange((u32*)&sent_row[j], (u32)(t + 1),
                                  __ATOMIC_RELAXED, __HIP_MEMORY_SCOPE_AGENT);
    }

    cstate[seq * HID + hc0]     = c0;
    cstate[seq * HID + hc0 + 1] = c1;
}

extern "C" void kernel_launch(void* const* d_in, const int* in_sizes, int n_in,
                              void* d_out, int out_size, void* d_ws, size_t ws_size,
                              hipStream_t stream)
{
    const float* x  = (const float*)d_in[0];
    const float* h0 = (const float*)d_in[1];
    const float* Wx = (const float*)d_in[2];
    const float* Wh = (const float*)d_in[3];
    const float* b  = (const float*)d_in[4];
    float* out = (float*)d_out;

    char* ws = (char*)d_ws;
    __bf16* WxbT   = (__bf16*)(ws);                                // 2 MB
    __bf16* WhbT   = (__bf16*)(ws + (2u << 20));                   // 2 MB
    __bf16* hcomm  = (__bf16*)(ws + (4u << 20));                   // 256 KB (8 slots)
    u32*    sent   = (u32*)(ws + (4u << 20) + (256u << 10));       // 128 B
    float*  cstate = (float*)(ws + (4u << 20) + (320u << 10));     // 64 KB
    float*  Axw    = (float*)(ws + (4u << 20) + (384u << 10));
    const size_t base = (4u << 20) + (384u << 10);

    // largest chunk Tc in {2048,...,16} whose A-buffer fits in ws
    int ltc = 11;
    while (ltc > 4 && base + (((size_t)NSEQ << ltc) * G4 * sizeof(float)) > ws_size) --ltc;
    const int Tc = 1 << ltc;

    lstm_init<<<dim3((G4 * DIM) / 256), dim3(256), 0, stream>>>(
        Wx, Wh, h0, WxbT, WhbT, hcomm, sent, cstate);

    for (int t0 = 0; t0 < TTOT; t0 += Tc) {
        gemm_xwx<<<dim3(G4 / 128, (NSEQ << ltc) / 128), dim3(256), 0, stream>>>(
            x, WxbT, b, Axw, t0, ltc);
        lstm_rec<<<dim3(32), dim3(256), 0, stream>>>(
            Axw, WhbT, hcomm, sent, cstate, out, t0, Tc);
    }
}